// Round 3
// baseline (2219.245 us; speedup 1.0000x reference)
//
#include <hip/hip_runtime.h>
#include <hip/hip_bf16.h>
#include <stdint.h>

// Problem constants
#define S_LEN 256
#define BATCH 64
#define HID   1024
#define RDIM  512
#define VOC   512
#define GATES 4096  // 4*HID

// d_out element offsets (fp32): logits [S][B][V], h [1][B][H], c [1][B][H], loss [1]
#define OFF_H    8388608u
#define OFF_C    8454144u
#define OFF_LOSS 8519680u

typedef __attribute__((ext_vector_type(8))) short short8;   // 8 x bf16 (4 VGPR)
typedef __attribute__((ext_vector_type(4))) float f32x4;
typedef unsigned long long u64;

#define HBUF_BYTES (128u * 1024u)  // one h fragment buffer: 4mt*32kk*64lane*16B
#define GBUF_STRIDE 68             // padded f32 row stride (kills 16-way bank conflict)

// ---------------- helpers ----------------

__device__ inline unsigned short f2bf(float f) {
  unsigned u = __builtin_bit_cast(unsigned, f);
  return (unsigned short)((u + 0x7FFFu + ((u >> 16) & 1u)) >> 16);
}

__device__ inline u64 pack4(float a, float b, float c, float d) {
  return (u64)f2bf(a) | ((u64)f2bf(b) << 16) | ((u64)f2bf(c) << 32) | ((u64)f2bf(d) << 48);
}

__device__ inline f32x4 mfma16(short8 a, short8 b, f32x4 c) {
  return __builtin_amdgcn_mfma_f32_16x16x32_bf16(a, b, c, 0, 0, 0);
}

// agent-scope (LLC-coherent, bypasses per-XCD L2) 16B fragment load
__device__ inline short8 ldfrag_sc(const char* p) {
  u64 lo = __hip_atomic_load((const u64*)p, __ATOMIC_RELAXED, __HIP_MEMORY_SCOPE_AGENT);
  u64 hi = __hip_atomic_load((const u64*)(p + 8), __ATOMIC_RELAXED, __HIP_MEMORY_SCOPE_AGENT);
  struct Pair { u64 a, b; } pr{lo, hi};
  return __builtin_bit_cast(short8, pr);
}

__device__ inline void stfrag8(char* p, u64 v) {
  __hip_atomic_store((u64*)p, v, __ATOMIC_RELAXED, __HIP_MEMORY_SCOPE_AGENT);
}

// fragment-layout byte offset of h element block (b, hcol..hcol+3), hcol % 4 == 0
__device__ inline size_t fragoff(int b, int hcol) {
  int mt = b >> 4, kk = hcol >> 5;
  int lane = (b & 15) + (((hcol >> 3) & 3) << 4);
  return ((((size_t)mt * 32 + kk) * 64 + lane) << 4) + (size_t)((hcol & 7) * 2);
}

__device__ inline float sigm(float x) {
  return __builtin_amdgcn_rcpf(1.f + __expf(-x));
}
__device__ inline float tanh_(float x) {
  return 1.f - 2.f * __builtin_amdgcn_rcpf(__expf(2.f * x) + 1.f);
}

// ---------------- prep: T table, fc_w->bf16, zero flags/loss ----------------
// grid 517 x 256
__global__ void __launch_bounds__(256) k_prep(
    const float* __restrict__ W_ih, const float* __restrict__ b_ih,
    const float* __restrict__ b_hh, const float* __restrict__ fc_w,
    float* __restrict__ T, unsigned short* __restrict__ fcw_bf,
    unsigned* __restrict__ flags, float* __restrict__ loss_slot)
{
  __shared__ float stage[64][65];
  const int bid = blockIdx.x, tid = threadIdx.x;
  if (bid < 512) {
    // T[e][c] = W_ih[c][e] + b_ih[c] + b_hh[c]  (64x64 transpose tile)
    const int c0 = (bid >> 3) * 64, e0 = (bid & 7) * 64;
    for (int idx = tid; idx < 4096; idx += 256) {
      int i = idx >> 6, jj = idx & 63;
      stage[i][jj] = W_ih[(size_t)(c0 + i) * RDIM + e0 + jj];
    }
    __syncthreads();
    for (int idx = tid; idx < 4096; idx += 256) {
      int jj = idx >> 6, i = idx & 63;
      int c = c0 + i;
      T[(size_t)(e0 + jj) * GATES + c] = stage[i][jj] + b_ih[c] + b_hh[c];
    }
  } else if (bid < 516) {
    // fc_w fp32 -> bf16
    const size_t off = (size_t)(bid - 512) * 131072;
    for (int k = tid; k < 32768; k += 256) {
      float4 v = *(const float4*)(fc_w + off + (size_t)k * 4);
      ushort4 o;
      o.x = f2bf(v.x); o.y = f2bf(v.y); o.z = f2bf(v.z); o.w = f2bf(v.w);
      *(ushort4*)(fcw_bf + off + (size_t)k * 4) = o;
    }
  } else {
    // zero flags (256 steps x 64 blocks x 4 waves) + loss accumulator
    for (int k = tid; k < 65536; k += 256)
      __hip_atomic_store(flags + k, 0u, __ATOMIC_RELAXED, __HIP_MEMORY_SCOPE_AGENT);
    if (tid == 0) loss_slot[0] = 0.f;
  }
}

// ---------------- persistent LSTM recurrence ----------------
// 64 blocks x 256 threads (4 waves). Block j owns h-cols [16j,16j+16) and the
// matching 64 gate columns. Wave w owns batch rows [16w,16w+16) — gbuf rows,
// cell state, h-ring fragments (mt=w) are all wave-private, so the step loop
// has NO barriers. Waves couple only via per-(block,wave) flags: 4 independent
// 64-CU "wave planes". A-fragments: flat 32-frag preload (one latency burst),
// unique per wave (1mt x 4nt tiling). Ring depth 2 (safe: a wave writes slot
// (t+1)&1 only after all wave-plane peers published h^t, which implies all
// finished reading h^{t-1} from that slot).
__global__ void __launch_bounds__(256, 1) k_recur(
    const float* __restrict__ W_hh, const float* __restrict__ Tt,
    const int* __restrict__ e_input, const float* __restrict__ emb,
    const int* __restrict__ cond, const float* __restrict__ d_input,
    const int* __restrict__ tf_ptr, const float* __restrict__ W_ih,
    const float* __restrict__ b_ih, const float* __restrict__ b_hh,
    char* __restrict__ hbuf, unsigned* __restrict__ flags,
    unsigned short* __restrict__ outs_r, float* __restrict__ dout)
{
  extern __shared__ char smem[];
  char* Wlds = smem;                         // 128 KiB B-fragments
  float* gbuf = (float*)(smem + 131072);     // 64 x GBUF_STRIDE fp32 (wave-private rows)
  const int j = blockIdx.x;
  const int tid = threadIdx.x;
  const int w = tid >> 6, l = tid & 63;
  const int tf = tf_ptr[0];

  // ---- pack W_hh slice into LDS fragments ----
  {
    const int nl = tid >> 2;        // local gate col 0..63 (gate = nl>>4)
    const int kq = tid & 3;
    const int g = nl >> 4, hc = nl & 15;
    const float* wrow = W_hh + (size_t)(g * HID + j * 16 + hc) * HID + kq * 256;
    for (int k8 = 0; k8 < 32; ++k8) {
      const int k = kq * 256 + k8 * 8;
      float4 va = *(const float4*)(wrow + k8 * 8);
      float4 vb = *(const float4*)(wrow + k8 * 8 + 4);
      u64 lo = pack4(va.x, va.y, va.z, va.w);
      u64 hi = pack4(vb.x, vb.y, vb.z, vb.w);
      const int kk = k >> 5;
      const int lane = (nl & 15) + (((k >> 3) & 3) << 4);
      char* p = Wlds + (((size_t)(g * 32 + kk) * 64 + lane) << 4);
      *(u64*)p = lo;
      *(u64*)(p + 8) = hi;
    }
  }

  // ---- h0 = c0 = emb[cond[b]] ----
  const int b = tid >> 2;           // global batch row = 16w + (l>>2)
  const int hcl = (tid & 3) * 4;
  const int hcol = j * 16 + hcl;
  float cr[4];
  {
    const int cd = cond[b];
    float4 h0 = *(const float4*)(emb + (size_t)cd * HID + hcol);
    cr[0] = h0.x; cr[1] = h0.y; cr[2] = h0.z; cr[3] = h0.w;
    u64 pk = pack4(h0.x, h0.y, h0.z, h0.w);
    stfrag8(hbuf + fragoff(b, hcol), pk);    // ring slot 0
  }
  asm volatile("s_waitcnt vmcnt(0)" ::: "memory");
  if (l == 0)
    __hip_atomic_store(flags + (size_t)j * 4 + w, 1u, __ATOMIC_RELAXED, __HIP_MEMORY_SCOPE_AGENT);
  __syncthreads();   // Wlds pack visible to all waves (only barrier in kernel)

  for (int t = 0; t < S_LEN; ++t) {
    // ---- T-table prefetch (independent of flags; hides under poll) ----
    float4 t0, t1, t2, t3;
    if (tf != 0) {
      const float* Trow = Tt + (size_t)e_input[t * BATCH + b] * GATES;
      t0 = *(const float4*)(Trow + 0 * HID + hcol);
      t1 = *(const float4*)(Trow + 1 * HID + hcol);
      t2 = *(const float4*)(Trow + 2 * HID + hcol);
      t3 = *(const float4*)(Trow + 3 * HID + hcol);
    }

    // ---- wait for wave-plane w of every block to publish h^t ----
    {
      const unsigned* fp = flags + ((size_t)t * 64 + l) * 4 + w;
      int guard = 0;
      while (__hip_atomic_load(fp, __ATOMIC_RELAXED, __HIP_MEMORY_SCOPE_AGENT) == 0u) {
        __builtin_amdgcn_s_sleep(1);
        if (++guard > (1 << 24)) break;   // safety valve: never hang
      }
    }

    // ---- flat A preload: 32 fragments (mt = w), one latency burst ----
    const char* hb = hbuf + (size_t)(t & 1) * HBUF_BYTES;
    short8 Afr[32];
#pragma unroll
    for (int kk = 0; kk < 32; ++kk)
      Afr[kk] = ldfrag_sc(hb + ((((size_t)w * 32 + kk) * 64 + l) << 4));

    // ---- gates_h = h^t @ Wslice^T : wave = 16 rows x 64 cols ----
    f32x4 acc[4];
    acc[0] = {0.f, 0.f, 0.f, 0.f}; acc[1] = {0.f, 0.f, 0.f, 0.f};
    acc[2] = {0.f, 0.f, 0.f, 0.f}; acc[3] = {0.f, 0.f, 0.f, 0.f};
#pragma unroll
    for (int kk = 0; kk < 32; ++kk) {
#pragma unroll
      for (int nt = 0; nt < 4; ++nt) {
        short8 B = *(const short8*)(Wlds + ((((size_t)nt * 32 + kk) * 64 + l) << 4));
        acc[nt] = mfma16(Afr[kk], B, acc[nt]);
      }
    }
    {
      const int rb = (l >> 4) * 4, cb = l & 15;
#pragma unroll
      for (int nt = 0; nt < 4; ++nt)
#pragma unroll
        for (int r = 0; r < 4; ++r)
          gbuf[(w * 16 + rb + r) * GBUF_STRIDE + nt * 16 + cb] = acc[nt][r];
    }
    // no barrier: gbuf rows [16w,16w+16) are wave-private (writer == reader)

    // ---- cell update: thread owns (b, hcol..hcol+3) ----
    float gv[4][4];  // [gate][r]
#pragma unroll
    for (int r = 0; r < 4; ++r) {
      gv[0][r] = gbuf[b * GBUF_STRIDE +  0 + hcl + r];
      gv[1][r] = gbuf[b * GBUF_STRIDE + 16 + hcl + r];
      gv[2][r] = gbuf[b * GBUF_STRIDE + 32 + hcl + r];
      gv[3][r] = gbuf[b * GBUF_STRIDE + 48 + hcl + r];
    }
    if (tf != 0) {
      gv[0][0] += t0.x; gv[0][1] += t0.y; gv[0][2] += t0.z; gv[0][3] += t0.w;
      gv[1][0] += t1.x; gv[1][1] += t1.y; gv[1][2] += t1.z; gv[1][3] += t1.w;
      gv[2][0] += t2.x; gv[2][1] += t2.y; gv[2][2] += t2.z; gv[2][3] += t2.w;
      gv[3][0] += t3.x; gv[3][1] += t3.y; gv[3][2] += t3.z; gv[3][3] += t3.w;
    } else {
      // dense path (unused in this bench, kept for semantic completeness)
      const float* x = d_input + ((size_t)t * BATCH + b) * RDIM;
#pragma unroll
      for (int g = 0; g < 4; ++g)
#pragma unroll
        for (int r = 0; r < 4; ++r) {
          const int row = g * HID + hcol + r;
          const float* wr = W_ih + (size_t)row * RDIM;
          float s = b_ih[row] + b_hh[row];
          for (int k = 0; k < RDIM; ++k) s += x[k] * wr[k];
          gv[g][r] += s;
        }
    }
    float hnew[4];
#pragma unroll
    for (int r = 0; r < 4; ++r) {
      float ig = sigm(gv[0][r]);
      float fg = sigm(gv[1][r]);
      float gg = tanh_(gv[2][r]);
      float og = sigm(gv[3][r]);
      cr[r] = fg * cr[r] + ig * gg;
      hnew[r] = og * tanh_(cr[r]);
    }
    const u64 pk = pack4(hnew[0], hnew[1], hnew[2], hnew[3]);
    // outs_r[j][t][b][0..15]: contiguous 2KB per (j,t), single-block-owned
    *(u64*)(outs_r + (size_t)j * 262144 + ((size_t)t * BATCH + b) * 16 + hcl) = pk;
    stfrag8(hbuf + (size_t)((t + 1) & 1) * HBUF_BYTES + fragoff(b, hcol), pk);
    if (t == S_LEN - 1) {
      *(float4*)(dout + OFF_H + (size_t)b * HID + hcol) = make_float4(hnew[0], hnew[1], hnew[2], hnew[3]);
      *(float4*)(dout + OFF_C + (size_t)b * HID + hcol) = make_float4(cr[0], cr[1], cr[2], cr[3]);
    }
    // per-wave drain, then publish this wave's slice of h^{t+1}
    asm volatile("s_waitcnt vmcnt(0)" ::: "memory");
    if (l == 0 && t < S_LEN - 1)
      __hip_atomic_store(flags + ((size_t)(t + 1) * 64 + j) * 4 + w, 1u,
                         __ATOMIC_RELAXED, __HIP_MEMORY_SCOPE_AGENT);
  }
}

// ---------------- projection: logits = outs @ fc_w^T + fc_b ----------------
// grid 2048 x 256, 64x64 tile per block; A is outs_r[j16][t][b][16]
__global__ void __launch_bounds__(256) k_gemm(
    const unsigned short* __restrict__ A,   // outs_r bf16 [64][256][64][16]
    const unsigned short* __restrict__ Bw,  // fc_w bf16 [512][1024]
    const float* __restrict__ fcb, float* __restrict__ C)
{
  const int bid = blockIdx.x;
  const int m0 = (bid >> 3) * 64, n0 = (bid & 7) * 64;
  const int tid = threadIdx.x, w = tid >> 6, l = tid & 63;
  const int mt0 = (w >> 1) * 2, nt0 = (w & 1) * 2;
  f32x4 acc[2][2];
  acc[0][0] = {0.f, 0.f, 0.f, 0.f}; acc[0][1] = {0.f, 0.f, 0.f, 0.f};
  acc[1][0] = {0.f, 0.f, 0.f, 0.f}; acc[1][1] = {0.f, 0.f, 0.f, 0.f};
  const int ksel  = (l >> 4) & 3;           // 0..3 -> k-offset selector
  const int jsel  = ksel >> 1;              // j16 sub-step 0,0,1,1
  const int koffL = (ksel & 1) * 8;         // 0,8,0,8
  const int m_a0 = m0 + mt0 * 16 + (l & 15);
  const unsigned short* a0p = A + (size_t)jsel * 262144 + (size_t)m_a0 * 16 + koffL;
  const unsigned short* a1p = a0p + 16 * 16;   // +16 rows of m -> +256 elems
  const int koff = ksel * 8;
  const unsigned short* b0p = Bw + (size_t)(n0 + nt0 * 16 + (l & 15)) * HID + koff;
  const unsigned short* b1p = b0p + 16 * HID;
#pragma unroll 4
  for (int kk = 0; kk < 32; ++kk) {
    short8 A0 = *(const short8*)(a0p + (size_t)kk * 524288);
    short8 A1 = *(const short8*)(a1p + (size_t)kk * 524288);
    short8 B0 = *(const short8*)(b0p + kk * 32);
    short8 B1 = *(const short8*)(b1p + kk * 32);
    acc[0][0] = mfma16(A0, B0, acc[0][0]);
    acc[0][1] = mfma16(A0, B1, acc[0][1]);
    acc[1][0] = mfma16(A1, B0, acc[1][0]);
    acc[1][1] = mfma16(A1, B1, acc[1][1]);
  }
  const int rb = (l >> 4) * 4, cb = l & 15;
#pragma unroll
  for (int i2 = 0; i2 < 2; ++i2)
#pragma unroll
    for (int j2 = 0; j2 < 2; ++j2) {
      const int n = n0 + (nt0 + j2) * 16 + cb;
      const float fb = fcb[n];
#pragma unroll
      for (int r = 0; r < 4; ++r) {
        const int m = m0 + (mt0 + i2) * 16 + rb + r;
        C[(size_t)m * VOC + n] = acc[i2][j2][r] + fb;
      }
    }
}

// ---------------- loss: -mean(logp[label]) ----------------
// grid 256 x 256 (4 waves x 16 rows each)
__global__ void __launch_bounds__(256) k_loss(
    const float* __restrict__ logits, const int* __restrict__ labels,
    float* __restrict__ dout)
{
  const int tid = threadIdx.x, w = tid >> 6, l = tid & 63;
  float part = 0.f;
  for (int i = 0; i < 16; ++i) {
    const int row = blockIdx.x * 64 + w * 16 + i;
    const float* lr = logits + (size_t)row * VOC;
    float4 x0 = *(const float4*)(lr + l * 8);
    float4 x1 = *(const float4*)(lr + l * 8 + 4);
    float v[8] = {x0.x, x0.y, x0.z, x0.w, x1.x, x1.y, x1.z, x1.w};
    float mx = v[0];
#pragma unroll
    for (int k = 1; k < 8; ++k) mx = fmaxf(mx, v[k]);
    for (int off = 32; off; off >>= 1) mx = fmaxf(mx, __shfl_xor(mx, off));
    float se = 0.f;
#pragma unroll
    for (int k = 0; k < 8; ++k) se += __expf(v[k] - mx);
    for (int off = 32; off; off >>= 1) se += __shfl_xor(se, off);
    const float lse = mx + __logf(se);
    const int lab = labels[row];
    const int li = lab - l * 8;
    float pick = v[0];
#pragma unroll
    for (int k = 1; k < 8; ++k) pick = (li == k) ? v[k] : pick;
    float term = (li >= 0 && li < 8) ? (lse - pick) : 0.f;
    for (int off = 32; off; off >>= 1) term += __shfl_xor(term, off);
    part += term;
  }
  if (l == 0) atomicAdd(dout + OFF_LOSS, part * (1.f / 16384.f));
}

// ---------------- host launch ----------------
extern "C" void kernel_launch(void* const* d_in, const int* in_sizes, int n_in,
                              void* d_out, int out_size, void* d_ws, size_t ws_size,
                              hipStream_t stream) {
  const float* d_input = (const float*)d_in[0];
  const int*   cond    = (const int*)d_in[1];
  const int*   e_input = (const int*)d_in[2];
  const int*   tf_ptr  = (const int*)d_in[3];
  const float* emb     = (const float*)d_in[4];
  const float* W_ih    = (const float*)d_in[5];
  const float* W_hh    = (const float*)d_in[6];
  const float* b_ih    = (const float*)d_in[7];
  const float* b_hh    = (const float*)d_in[8];
  const float* fc_w    = (const float*)d_in[9];
  const float* fc_b    = (const float*)d_in[10];
  float* out = (float*)d_out;
  char*  ws  = (char*)d_ws;

  // ws layout (bytes)
  const size_t WS_T    = 0;                        // 8 MiB fp32 T[512][4096]
  const size_t WS_FCW  = 8388608;                  // 1 MiB bf16 fc_w
  const size_t WS_OUTS = 9437184;                  // 32 MiB bf16 outs_r[64][256][64][16]
  const size_t WS_HBUF = 42991616;                 // h fragment ring (2 x 128 KiB)
  const size_t WS_FLAG = WS_HBUF + 2ull * HBUF_BYTES;  // 256 KiB flags
  char* hbuf = ws + WS_HBUF;
  unsigned* flags = (unsigned*)(ws + WS_FLAG);
  float* T = (float*)(ws + WS_T);
  unsigned short* fcw  = (unsigned short*)(ws + WS_FCW);
  unsigned short* outs = (unsigned short*)(ws + WS_OUTS);

  hipFuncSetAttribute((const void*)k_recur,
                      hipFuncAttributeMaxDynamicSharedMemorySize, 149504);

  k_prep<<<dim3(517), dim3(256), 0, stream>>>(W_ih, b_ih, b_hh, fc_w, T, fcw,
                                              flags, out + OFF_LOSS);
  k_recur<<<dim3(64), dim3(256), 149504, stream>>>(
      W_hh, T, e_input, emb, cond, d_input, tf_ptr, W_ih, b_ih, b_hh,
      hbuf, flags, outs, out);
  k_gemm<<<dim3(2048), dim3(256), 0, stream>>>(outs, fcw, fc_b, out);
  k_loss<<<dim3(256), dim3(256), 0, stream>>>(out, e_input, out);
}

// Round 4
// 1528.354 us; speedup vs baseline: 1.4520x; 1.4520x over previous
//
#include <hip/hip_runtime.h>
#include <hip/hip_bf16.h>
#include <stdint.h>

// Problem constants
#define S_LEN 256
#define BATCH 64
#define HID   1024
#define RDIM  512
#define VOC   512
#define GATES 4096  // 4*HID

// d_out element offsets (fp32): logits [S][B][V], h [1][B][H], c [1][B][H], loss [1]
#define OFF_H    8388608u
#define OFF_C    8454144u
#define OFF_LOSS 8519680u

typedef __attribute__((ext_vector_type(8))) short short8;   // 8 x bf16 (4 VGPR)
typedef __attribute__((ext_vector_type(4))) float f32x4;
typedef __attribute__((ext_vector_type(4))) int   i32x4;
typedef unsigned long long u64;

#define HBUF_BYTES (128u * 1024u)  // one h fragment buffer: 4mt*32kk*64lane*16B
#define GT_S 65                    // transposed gate-buf stride (f32 words)

// ---------------- helpers ----------------

__device__ inline unsigned short f2bf(float f) {
  unsigned u = __builtin_bit_cast(unsigned, f);
  return (unsigned short)((u + 0x7FFFu + ((u >> 16) & 1u)) >> 16);
}

__device__ inline u64 pack4(float a, float b, float c, float d) {
  return (u64)f2bf(a) | ((u64)f2bf(b) << 16) | ((u64)f2bf(c) << 32) | ((u64)f2bf(d) << 48);
}

__device__ inline f32x4 mfma16(short8 a, short8 b, f32x4 c) {
  return __builtin_amdgcn_mfma_f32_16x16x32_bf16(a, b, c, 0, 0, 0);
}

__device__ inline void stfrag8(char* p, u64 v) {
  __hip_atomic_store((u64*)p, v, __ATOMIC_RELAXED, __HIP_MEMORY_SCOPE_AGENT);
}

// fragment-layout byte offset of h element block (b, hcol..hcol+3), hcol % 4 == 0
__device__ inline size_t fragoff(int b, int hcol) {
  int mt = b >> 4, kk = hcol >> 5;
  int lane = (b & 15) + (((hcol >> 3) & 3) << 4);
  return ((((size_t)mt * 32 + kk) * 64 + lane) << 4) + (size_t)((hcol & 7) * 2);
}

__device__ inline float sigm(float x) {
  return __builtin_amdgcn_rcpf(1.f + __expf(-x));
}
__device__ inline float tanh_(float x) {
  return 1.f - 2.f * __builtin_amdgcn_rcpf(__expf(2.f * x) + 1.f);
}

// ---------------- prep: T table, fc_w->bf16, zero flags/loss ----------------
// grid 517 x 256
__global__ void __launch_bounds__(256) k_prep(
    const float* __restrict__ W_ih, const float* __restrict__ b_ih,
    const float* __restrict__ b_hh, const float* __restrict__ fc_w,
    float* __restrict__ T, unsigned short* __restrict__ fcw_bf,
    unsigned* __restrict__ flags, float* __restrict__ loss_slot)
{
  __shared__ float stage[64][65];
  const int bid = blockIdx.x, tid = threadIdx.x;
  if (bid < 512) {
    // T[e][c] = W_ih[c][e] + b_ih[c] + b_hh[c]  (64x64 transpose tile)
    const int c0 = (bid >> 3) * 64, e0 = (bid & 7) * 64;
    for (int idx = tid; idx < 4096; idx += 256) {
      int i = idx >> 6, jj = idx & 63;
      stage[i][jj] = W_ih[(size_t)(c0 + i) * RDIM + e0 + jj];
    }
    __syncthreads();
    for (int idx = tid; idx < 4096; idx += 256) {
      int jj = idx >> 6, i = idx & 63;
      int c = c0 + i;
      T[(size_t)(e0 + jj) * GATES + c] = stage[i][jj] + b_ih[c] + b_hh[c];
    }
  } else if (bid < 516) {
    // fc_w fp32 -> bf16
    const size_t off = (size_t)(bid - 512) * 131072;
    for (int k = tid; k < 32768; k += 256) {
      float4 v = *(const float4*)(fc_w + off + (size_t)k * 4);
      ushort4 o;
      o.x = f2bf(v.x); o.y = f2bf(v.y); o.z = f2bf(v.z); o.w = f2bf(v.w);
      *(ushort4*)(fcw_bf + off + (size_t)k * 4) = o;
    }
  } else {
    // zero flags (write-through to LLC) + loss accumulator
    for (int k = tid; k < 65536; k += 256)
      __hip_atomic_store(flags + k, 0u, __ATOMIC_RELAXED, __HIP_MEMORY_SCOPE_AGENT);
    if (tid == 0) loss_slot[0] = 0.f;
  }
}

// ---------------- persistent LSTM recurrence ----------------
// 64 blocks x 256 threads (4 waves). Block j owns h-cols [16j,16j+16) and the
// matching 64 gate columns. Wave w owns batch rows [16w,16w+16): unique A per
// wave (1mt x 4nt tiling). Sync: block-wide flag per step (R2-proven), two
// __syncthreads per step. A-fragments fetched from the LLC ring with an
// inline-asm BURST of 32 global_load_dwordx4 sc0 sc1 (L1/L2-bypass), one
// s_waitcnt vmcnt(0), sched_barrier(0): exactly one exposed LLC latency per
// step instead of 32 (R3's compiler-serialized atomic loads).
__global__ void __launch_bounds__(256, 1) k_recur(
    const float* __restrict__ W_hh, const float* __restrict__ Tt,
    const int* __restrict__ e_input, const float* __restrict__ emb,
    const int* __restrict__ cond, const float* __restrict__ d_input,
    const int* __restrict__ tf_ptr, const float* __restrict__ W_ih,
    const float* __restrict__ b_ih, const float* __restrict__ b_hh,
    char* __restrict__ hbuf, unsigned* __restrict__ flags,
    unsigned short* __restrict__ outs_r, float* __restrict__ dout)
{
  extern __shared__ char smem[];
  char* Wlds = smem;                         // 128 KiB B-fragments
  float* gbufT = (float*)(smem + 131072);    // [64 gatecols][GT_S] transposed
  const int j = blockIdx.x;
  const int tid = threadIdx.x;
  const int w = tid >> 6, l = tid & 63;
  const int tf = tf_ptr[0];

  // ---- pack W_hh slice into LDS fragments (16x16x32 B-layout) ----
  {
    const int nl = tid >> 2;        // local gate col 0..63 (gate = nl>>4)
    const int kq = tid & 3;
    const int g = nl >> 4, hc = nl & 15;
    const float* wrow = W_hh + (size_t)(g * HID + j * 16 + hc) * HID + kq * 256;
    for (int k8 = 0; k8 < 32; ++k8) {
      const int k = kq * 256 + k8 * 8;
      float4 va = *(const float4*)(wrow + k8 * 8);
      float4 vb = *(const float4*)(wrow + k8 * 8 + 4);
      u64 lo = pack4(va.x, va.y, va.z, va.w);
      u64 hi = pack4(vb.x, vb.y, vb.z, vb.w);
      const int kk = k >> 5;
      const int lane = (nl & 15) + (((k >> 3) & 3) << 4);
      char* p = Wlds + (((size_t)(g * 32 + kk) * 64 + lane) << 4);
      *(u64*)p = lo;
      *(u64*)(p + 8) = hi;
    }
  }

  // ---- h0 = c0 = emb[cond[b]] ----
  const int b = tid >> 2;           // global batch row = 16w + (l>>2)
  const int hcl = (tid & 3) * 4;
  const int hcol = j * 16 + hcl;
  float cr[4];
  {
    const int cd = cond[b];
    float4 h0 = *(const float4*)(emb + (size_t)cd * HID + hcol);
    cr[0] = h0.x; cr[1] = h0.y; cr[2] = h0.z; cr[3] = h0.w;
    u64 pk = pack4(h0.x, h0.y, h0.z, h0.w);
    stfrag8(hbuf + fragoff(b, hcol), pk);    // ring slot 0
  }
  asm volatile("s_waitcnt vmcnt(0)" ::: "memory");
  __syncthreads();   // h0 stores drained by all waves; Wlds pack complete
  if (tid == 0)
    __hip_atomic_store(flags + j, 1u, __ATOMIC_RELAXED, __HIP_MEMORY_SCOPE_AGENT);

  for (int t = 0; t < S_LEN; ++t) {
    // ---- T-table prefetch (independent of flags; hides under poll) ----
    float4 t0, t1, t2, t3;
    if (tf != 0) {
      const float* Trow = Tt + (size_t)e_input[t * BATCH + b] * GATES;
      t0 = *(const float4*)(Trow + 0 * HID + hcol);
      t1 = *(const float4*)(Trow + 1 * HID + hcol);
      t2 = *(const float4*)(Trow + 2 * HID + hcol);
      t3 = *(const float4*)(Trow + 3 * HID + hcol);
    }

    // ---- wait for every block to publish h^t (64 pollers) ----
    if (tid < 64) {
      const unsigned* fp = flags + (size_t)t * 64 + tid;
      int guard = 0;
      while (__hip_atomic_load(fp, __ATOMIC_RELAXED, __HIP_MEMORY_SCOPE_AGENT) == 0u) {
        __builtin_amdgcn_s_sleep(1);
        if (++guard > (1 << 24)) break;   // safety valve: never hang
      }
    }
    __syncthreads();

    // ---- A-fragment BURST: 32 x global_load_dwordx4 sc0 sc1 in flight,
    //      one vmcnt(0), sched_barrier. mt = w (wave-unique rows). ----
    const char* hb = hbuf + (size_t)(t & 1) * HBUF_BYTES;
    const char* ap = hb + (((size_t)w * 32 * 64 + l) << 4);  // kk stride 1024B
    i32x4 a[32];
#pragma unroll
    for (int kk = 0; kk < 32; ++kk) {
      asm volatile("global_load_dwordx4 %0, %1, off sc0 sc1"
                   : "=v"(a[kk]) : "v"(ap + (size_t)kk * 1024));
    }
    asm volatile("s_waitcnt vmcnt(0)" ::: "memory");
    __builtin_amdgcn_sched_barrier(0);

    // ---- gates_h = h^t @ Wslice^T : wave = 16 rows x 64 cols ----
    f32x4 acc[4];
    acc[0] = {0.f, 0.f, 0.f, 0.f}; acc[1] = {0.f, 0.f, 0.f, 0.f};
    acc[2] = {0.f, 0.f, 0.f, 0.f}; acc[3] = {0.f, 0.f, 0.f, 0.f};
#pragma unroll
    for (int kk = 0; kk < 32; ++kk) {
      const short8 A = __builtin_bit_cast(short8, a[kk]);
#pragma unroll
      for (int nt = 0; nt < 4; ++nt) {
        short8 B = *(const short8*)(Wlds + ((((size_t)nt * 32 + kk) * 64 + l) << 4));
        acc[nt] = mfma16(A, B, acc[nt]);
      }
    }
    // transposed gbuf write: ~2-way banks (free). col=nt*16+(l&15), row=...
    {
      const int rb = (l >> 4) * 4, cb = l & 15;
#pragma unroll
      for (int nt = 0; nt < 4; ++nt)
#pragma unroll
        for (int r = 0; r < 4; ++r)
          gbufT[(nt * 16 + cb) * GT_S + w * 16 + rb + r] = acc[nt][r];
    }
    // no barrier: rows [16w,16w+16) are wave-private (writer == reader)

    // ---- cell update: thread owns (b, hcol..hcol+3) ----
    float gv[4][4];  // [gate][r]
#pragma unroll
    for (int g = 0; g < 4; ++g)
#pragma unroll
      for (int r = 0; r < 4; ++r)
        gv[g][r] = gbufT[(g * 16 + hcl + r) * GT_S + b];
    if (tf != 0) {
      gv[0][0] += t0.x; gv[0][1] += t0.y; gv[0][2] += t0.z; gv[0][3] += t0.w;
      gv[1][0] += t1.x; gv[1][1] += t1.y; gv[1][2] += t1.z; gv[1][3] += t1.w;
      gv[2][0] += t2.x; gv[2][1] += t2.y; gv[2][2] += t2.z; gv[2][3] += t2.w;
      gv[3][0] += t3.x; gv[3][1] += t3.y; gv[3][2] += t3.z; gv[3][3] += t3.w;
    } else {
      // dense path (unused in this bench, kept for semantic completeness)
      const float* x = d_input + ((size_t)t * BATCH + b) * RDIM;
#pragma unroll
      for (int g = 0; g < 4; ++g)
#pragma unroll
        for (int r = 0; r < 4; ++r) {
          const int row = g * HID + hcol + r;
          const float* wr = W_ih + (size_t)row * RDIM;
          float s = b_ih[row] + b_hh[row];
          for (int k = 0; k < RDIM; ++k) s += x[k] * wr[k];
          gv[g][r] += s;
        }
    }
    float hnew[4];
#pragma unroll
    for (int r = 0; r < 4; ++r) {
      float ig = sigm(gv[0][r]);
      float fg = sigm(gv[1][r]);
      float gg = tanh_(gv[2][r]);
      float og = sigm(gv[3][r]);
      cr[r] = fg * cr[r] + ig * gg;
      hnew[r] = og * tanh_(cr[r]);
    }
    const u64 pk = pack4(hnew[0], hnew[1], hnew[2], hnew[3]);
    // outs_r[j][t][b][0..15]: contiguous 2KB per (j,t), single-block-owned
    *(u64*)(outs_r + (size_t)j * 262144 + ((size_t)t * BATCH + b) * 16 + hcl) = pk;
    stfrag8(hbuf + (size_t)((t + 1) & 1) * HBUF_BYTES + fragoff(b, hcol), pk);
    if (t == S_LEN - 1) {
      *(float4*)(dout + OFF_H + (size_t)b * HID + hcol) = make_float4(hnew[0], hnew[1], hnew[2], hnew[3]);
      *(float4*)(dout + OFF_C + (size_t)b * HID + hcol) = make_float4(cr[0], cr[1], cr[2], cr[3]);
    }
    // drain all waves' stores, then publish h^{t+1}
    asm volatile("s_waitcnt vmcnt(0)" ::: "memory");
    __syncthreads();
    if (tid == 0 && t < S_LEN - 1)
      __hip_atomic_store(flags + (size_t)(t + 1) * 64 + j, 1u,
                         __ATOMIC_RELAXED, __HIP_MEMORY_SCOPE_AGENT);
  }
}

// ---------------- projection: logits = outs @ fc_w^T + fc_b ----------------
// grid 2048 x 256, 64x64 tile per block; A is outs_r[j16][t][b][16]
__global__ void __launch_bounds__(256) k_gemm(
    const unsigned short* __restrict__ A,   // outs_r bf16 [64][256][64][16]
    const unsigned short* __restrict__ Bw,  // fc_w bf16 [512][1024]
    const float* __restrict__ fcb, float* __restrict__ C)
{
  const int bid = blockIdx.x;
  const int m0 = (bid >> 3) * 64, n0 = (bid & 7) * 64;
  const int tid = threadIdx.x, w = tid >> 6, l = tid & 63;
  const int mt0 = (w >> 1) * 2, nt0 = (w & 1) * 2;
  f32x4 acc[2][2];
  acc[0][0] = {0.f, 0.f, 0.f, 0.f}; acc[0][1] = {0.f, 0.f, 0.f, 0.f};
  acc[1][0] = {0.f, 0.f, 0.f, 0.f}; acc[1][1] = {0.f, 0.f, 0.f, 0.f};
  const int ksel  = (l >> 4) & 3;           // 0..3 -> k-offset selector
  const int jsel  = ksel >> 1;              // j16 sub-step 0,0,1,1
  const int koffL = (ksel & 1) * 8;         // 0,8,0,8
  const int m_a0 = m0 + mt0 * 16 + (l & 15);
  const unsigned short* a0p = A + (size_t)jsel * 262144 + (size_t)m_a0 * 16 + koffL;
  const unsigned short* a1p = a0p + 16 * 16;   // +16 rows of m -> +256 elems
  const int koff = ksel * 8;
  const unsigned short* b0p = Bw + (size_t)(n0 + nt0 * 16 + (l & 15)) * HID + koff;
  const unsigned short* b1p = b0p + 16 * HID;
#pragma unroll 4
  for (int kk = 0; kk < 32; ++kk) {
    short8 A0 = *(const short8*)(a0p + (size_t)kk * 524288);
    short8 A1 = *(const short8*)(a1p + (size_t)kk * 524288);
    short8 B0 = *(const short8*)(b0p + kk * 32);
    short8 B1 = *(const short8*)(b1p + kk * 32);
    acc[0][0] = mfma16(A0, B0, acc[0][0]);
    acc[0][1] = mfma16(A0, B1, acc[0][1]);
    acc[1][0] = mfma16(A1, B0, acc[1][0]);
    acc[1][1] = mfma16(A1, B1, acc[1][1]);
  }
  const int rb = (l >> 4) * 4, cb = l & 15;
#pragma unroll
  for (int i2 = 0; i2 < 2; ++i2)
#pragma unroll
    for (int j2 = 0; j2 < 2; ++j2) {
      const int n = n0 + (nt0 + j2) * 16 + cb;
      const float fb = fcb[n];
#pragma unroll
      for (int r = 0; r < 4; ++r) {
        const int m = m0 + (mt0 + i2) * 16 + rb + r;
        C[(size_t)m * VOC + n] = acc[i2][j2][r] + fb;
      }
    }
}

// ---------------- loss: -mean(logp[label]) ----------------
// grid 256 x 256 (4 waves x 16 rows each)
__global__ void __launch_bounds__(256) k_loss(
    const float* __restrict__ logits, const int* __restrict__ labels,
    float* __restrict__ dout)
{
  const int tid = threadIdx.x, w = tid >> 6, l = tid & 63;
  float part = 0.f;
  for (int i = 0; i < 16; ++i) {
    const int row = blockIdx.x * 64 + w * 16 + i;
    const float* lr = logits + (size_t)row * VOC;
    float4 x0 = *(const float4*)(lr + l * 8);
    float4 x1 = *(const float4*)(lr + l * 8 + 4);
    float v[8] = {x0.x, x0.y, x0.z, x0.w, x1.x, x1.y, x1.z, x1.w};
    float mx = v[0];
#pragma unroll
    for (int k = 1; k < 8; ++k) mx = fmaxf(mx, v[k]);
    for (int off = 32; off; off >>= 1) mx = fmaxf(mx, __shfl_xor(mx, off));
    float se = 0.f;
#pragma unroll
    for (int k = 0; k < 8; ++k) se += __expf(v[k] - mx);
    for (int off = 32; off; off >>= 1) se += __shfl_xor(se, off);
    const float lse = mx + __logf(se);
    const int lab = labels[row];
    const int li = lab - l * 8;
    float pick = v[0];
#pragma unroll
    for (int k = 1; k < 8; ++k) pick = (li == k) ? v[k] : pick;
    float term = (li >= 0 && li < 8) ? (lse - pick) : 0.f;
    for (int off = 32; off; off >>= 1) term += __shfl_xor(term, off);
    part += term;
  }
  if (l == 0) atomicAdd(dout + OFF_LOSS, part * (1.f / 16384.f));
}

// ---------------- host launch ----------------
extern "C" void kernel_launch(void* const* d_in, const int* in_sizes, int n_in,
                              void* d_out, int out_size, void* d_ws, size_t ws_size,
                              hipStream_t stream) {
  const float* d_input = (const float*)d_in[0];
  const int*   cond    = (const int*)d_in[1];
  const int*   e_input = (const int*)d_in[2];
  const int*   tf_ptr  = (const int*)d_in[3];
  const float* emb     = (const float*)d_in[4];
  const float* W_ih    = (const float*)d_in[5];
  const float* W_hh    = (const float*)d_in[6];
  const float* b_ih    = (const float*)d_in[7];
  const float* b_hh    = (const float*)d_in[8];
  const float* fc_w    = (const float*)d_in[9];
  const float* fc_b    = (const float*)d_in[10];
  float* out = (float*)d_out;
  char*  ws  = (char*)d_ws;

  // ws layout (bytes)
  const size_t WS_T    = 0;                        // 8 MiB fp32 T[512][4096]
  const size_t WS_FCW  = 8388608;                  // 1 MiB bf16 fc_w
  const size_t WS_OUTS = 9437184;                  // 32 MiB bf16 outs_r[64][256][64][16]
  const size_t WS_HBUF = 42991616;                 // h fragment ring (2 x 128 KiB)
  const size_t WS_FLAG = WS_HBUF + 2ull * HBUF_BYTES;  // 256 KiB flags
  char* hbuf = ws + WS_HBUF;
  unsigned* flags = (unsigned*)(ws + WS_FLAG);
  float* T = (float*)(ws + WS_T);
  unsigned short* fcw  = (unsigned short*)(ws + WS_FCW);
  unsigned short* outs = (unsigned short*)(ws + WS_OUTS);

  const int ldsz = 131072 + 64 * GT_S * 4;   // Wlds + transposed gbuf
  hipFuncSetAttribute((const void*)k_recur,
                      hipFuncAttributeMaxDynamicSharedMemorySize, ldsz);

  k_prep<<<dim3(517), dim3(256), 0, stream>>>(W_ih, b_ih, b_hh, fc_w, T, fcw,
                                              flags, out + OFF_LOSS);
  k_recur<<<dim3(64), dim3(256), ldsz, stream>>>(
      W_hh, T, e_input, emb, cond, d_input, tf_ptr, W_ih, b_ih, b_hh,
      hbuf, flags, outs, out);
  k_gemm<<<dim3(2048), dim3(256), 0, stream>>>(outs, fcw, fc_b, out);
  k_loss<<<dim3(256), dim3(256), 0, stream>>>(out, e_input, out);
}